// Round 5
// baseline (24.202 us; speedup 1.0000x reference)
//
#include <hip/hip_runtime.h>
#include <stdint.h>

// ACOLayer: reproduce JAX's sampling exactly.
//   u = jax.random.uniform(key(42), (32, 4096, 16), f32)
//   idx[b,i,a] = searchsorted(cdf_row_i, u[b,i,a]) clamped; -1 where a >= x[b,i]
// RNG: jax_threefry_partitionable=True stream:
//   bits[i] = o0 ^ o1, (o0,o1) = threefry2x32(key=(0,42), counter=(0, i))
//   u = bitcast((bits>>9)|0x3f800000) - 1.0f
// Structure: 2048 blocks x 2 rows, software-pipelined: row B's global loads +
// threefry overlap row A's LDS binary-search phase (breaks the load/compute
// phase convoy that serialized HBM and LDS in the 1-row-per-block version).

#define N_IN    4096
#define N_OUT   4096
#define BS      32
#define MAX_A   16
#define THREADS 256
#define HALF    1048576u  /* 16 * N_IN * MAX_A */
#define GRID    (N_IN / 2)

// pad +4 floats per 64: breaks power-of-2 bank strides, keeps 16-chunks contiguous
__device__ __forceinline__ int padi(int j) { return j + ((j >> 6) << 2); }

__device__ __forceinline__ uint32_t rotl32(uint32_t x, uint32_t r) {
    return (x << r) | (x >> (32u - r));
}

// Threefry-2x32, 20 rounds, key (0, 42) — jax.random.key(42)
__device__ __forceinline__ void threefry2x32_42(uint32_t x0, uint32_t x1,
                                                uint32_t& o0, uint32_t& o1) {
    const uint32_t k0 = 0u, k1 = 42u;
    const uint32_t k2 = k0 ^ k1 ^ 0x1BD11BDAu;
    x0 += k0; x1 += k1;
#define TF_R(r) { x0 += x1; x1 = rotl32(x1, (r)); x1 ^= x0; }
    TF_R(13) TF_R(15) TF_R(26) TF_R(6)
    x0 += k1; x1 += k2 + 1u;
    TF_R(17) TF_R(29) TF_R(16) TF_R(24)
    x0 += k2; x1 += k0 + 2u;
    TF_R(13) TF_R(15) TF_R(26) TF_R(6)
    x0 += k0; x1 += k1 + 3u;
    TF_R(17) TF_R(29) TF_R(16) TF_R(24)
    x0 += k1; x1 += k2 + 4u;
    TF_R(13) TF_R(15) TF_R(26) TF_R(6)
    x0 += k2; x1 += k0 + 5u;
#undef TF_R
    o0 = x0; o1 = x1;
}

__device__ __forceinline__ float bits_to_uniform(uint32_t b) {
    uint32_t f = (b >> 9) | 0x3f800000u;
    float r;
    __builtin_memcpy(&r, &f, 4);
    return r - 1.0f;
}

// fixed 12-step lower_bound on padded LDS cdf (no divergence)
__device__ __forceinline__ int lower_bound_cdf(const float* cdf, float tval) {
    int lo = 0, hi = N_OUT;
    #pragma unroll
    for (int it = 0; it < 12; ++it) {
        int mid = (lo + hi) >> 1;
        if (cdf[padi(mid)] < tval) lo = mid + 1; else hi = mid;
    }
    return lo < N_OUT ? lo : N_OUT - 1;
}

// register scan of 16 staged values -> loc[16]; returns loc[15]
__device__ __forceinline__ float local_scan16(const float4& v0, const float4& v1,
                                              const float4& v2, const float4& v3,
                                              float* loc) {
    float s = 0.f;
    s += v0.x; loc[0]  = s;  s += v0.y; loc[1]  = s;
    s += v0.z; loc[2]  = s;  s += v0.w; loc[3]  = s;
    s += v1.x; loc[4]  = s;  s += v1.y; loc[5]  = s;
    s += v1.z; loc[6]  = s;  s += v1.w; loc[7]  = s;
    s += v2.x; loc[8]  = s;  s += v2.y; loc[9]  = s;
    s += v2.z; loc[10] = s;  s += v2.w; loc[11] = s;
    s += v3.x; loc[12] = s;  s += v3.y; loc[13] = s;
    s += v3.z; loc[14] = s;  s += v3.w; loc[15] = s;
    return s;
}

__device__ __forceinline__ void write_cdf16(float* cbase, const float* loc, float pfx) {
    float4 a, b, c, d;
    a.x = pfx + loc[0];  a.y = pfx + loc[1];  a.z = pfx + loc[2];  a.w = pfx + loc[3];
    b.x = pfx + loc[4];  b.y = pfx + loc[5];  b.z = pfx + loc[6];  b.w = pfx + loc[7];
    c.x = pfx + loc[8];  c.y = pfx + loc[9];  c.z = pfx + loc[10]; c.w = pfx + loc[11];
    d.x = pfx + loc[12]; d.y = pfx + loc[13]; d.z = pfx + loc[14]; d.w = pfx + loc[15];
    ((float4*)cbase)[0] = a;
    ((float4*)cbase)[1] = b;
    ((float4*)cbase)[2] = c;
    ((float4*)cbase)[3] = d;
}

__global__ __launch_bounds__(THREADS)
void aco_sample_kernel(const int* __restrict__ x,
                       const float* __restrict__ w,
                       int* __restrict__ out) {
    __shared__ float cdf[N_OUT + (N_OUT >> 4)];
    __shared__ float wsum[4];
    __shared__ int   xc[2][BS];

    const int t    = threadIdx.x;
    const int lane = t & 63;
    const int wid  = t >> 6;
    const int row0 = blockIdx.x;
    const int row1 = blockIdx.x + GRID;

    // ---- prologue: stage row A weights + both rows' x columns ----
    const float4* wr0 = (const float4*)(w + (size_t)row0 * N_OUT);
    float4 a0 = wr0[t * 4 + 0];
    float4 a1 = wr0[t * 4 + 1];
    float4 a2 = wr0[t * 4 + 2];
    float4 a3 = wr0[t * 4 + 3];
    if (t < BS)           xc[0][t]      = x[t * N_IN + row0];
    else if (t < 2 * BS)  xc[1][t - BS] = x[(t - BS) * N_IN + row1];

    // ---- RNG for row A (pure VALU, fills the load-wait window) ----
    const int bb = t >> 4;
    const int aa = t & 15;
    const uint32_t jA = (uint32_t)(bb * (N_IN * MAX_A) + row0 * MAX_A + aa);
    uint32_t o0, o1, p0, p1;
    threefry2x32_42(0u, jA, o0, o1);
    threefry2x32_42(0u, jA + HALF, p0, p1);
    const float uA0 = bits_to_uniform(o0 ^ o1);
    const float uA1 = bits_to_uniform(p0 ^ p1);

    // ---- scan row A ----
    float loc[16];
    float my_total = local_scan16(a0, a1, a2, a3, loc);
    float incl = my_total;
    #pragma unroll
    for (int d = 1; d < 64; d <<= 1) {
        float n = __shfl_up(incl, d, 64);
        if (lane >= d) incl += n;
    }
    if (lane == 63) wsum[wid] = incl;
    __syncthreads();                       // B1: wsum A visible

    float4 ws = *(const float4*)wsum;
    const float totalA = ws.x + ws.y + ws.z + ws.w;
    {
        float wprefix = 0.f;
        if (wid > 0) wprefix += ws.x;
        if (wid > 1) wprefix += ws.y;
        if (wid > 2) wprefix += ws.z;
        write_cdf16(&cdf[padi(t * 16)], loc, wprefix + incl - my_total);
    }
    __syncthreads();                       // B2: cdf A complete

    // ---- issue row B loads + RNG B (overlaps row A search below) ----
    const float4* wr1 = (const float4*)(w + (size_t)row1 * N_OUT);
    float4 b0 = wr1[t * 4 + 0];
    float4 b1 = wr1[t * 4 + 1];
    float4 b2 = wr1[t * 4 + 2];
    float4 b3 = wr1[t * 4 + 3];
    const uint32_t jB = (uint32_t)(bb * (N_IN * MAX_A) + row1 * MAX_A + aa);
    threefry2x32_42(0u, jB, o0, o1);
    threefry2x32_42(0u, jB + HALF, p0, p1);
    const float uB0 = bits_to_uniform(o0 ^ o1);
    const float uB1 = bits_to_uniform(p0 ^ p1);

    // ---- search + store row A ----
    {
        const int idx0 = lower_bound_cdf(cdf, uA0 * totalA);
        const int idx1 = lower_bound_cdf(cdf, uA1 * totalA);
        out[jA]        = (aa < xc[0][bb])      ? idx0 : -1;
        out[jA + HALF] = (aa < xc[0][bb + 16]) ? idx1 : -1;
    }

    // ---- scan row B (shfl is register-only; waits on B loads here) ----
    my_total = local_scan16(b0, b1, b2, b3, loc);
    incl = my_total;
    #pragma unroll
    for (int d = 1; d < 64; d <<= 1) {
        float n = __shfl_up(incl, d, 64);
        if (lane >= d) incl += n;
    }
    // wsum A last read before B2; safe to overwrite now, made visible by B3
    if (lane == 63) wsum[wid] = incl;
    __syncthreads();                       // B3: cdf A free + wsum B visible

    ws = *(const float4*)wsum;
    const float totalB = ws.x + ws.y + ws.z + ws.w;
    {
        float wprefix = 0.f;
        if (wid > 0) wprefix += ws.x;
        if (wid > 1) wprefix += ws.y;
        if (wid > 2) wprefix += ws.z;
        write_cdf16(&cdf[padi(t * 16)], loc, wprefix + incl - my_total);
    }
    __syncthreads();                       // B4: cdf B complete

    // ---- search + store row B ----
    {
        const int idx0 = lower_bound_cdf(cdf, uB0 * totalB);
        const int idx1 = lower_bound_cdf(cdf, uB1 * totalB);
        out[jB]        = (aa < xc[1][bb])      ? idx0 : -1;
        out[jB + HALF] = (aa < xc[1][bb + 16]) ? idx1 : -1;
    }
}

extern "C" void kernel_launch(void* const* d_in, const int* in_sizes, int n_in,
                              void* d_out, int out_size, void* d_ws, size_t ws_size,
                              hipStream_t stream) {
    // select inputs by size (robust to ordering):
    //   x: 32*4096 int32; weights: 4096*4096 f32
    const int*   x;
    const float* w;
    if (in_sizes[0] == BS * N_IN) { x = (const int*)d_in[0]; w = (const float*)d_in[1]; }
    else                          { x = (const int*)d_in[1]; w = (const float*)d_in[0]; }
    aco_sample_kernel<<<GRID, THREADS, 0, stream>>>(x, w, (int*)d_out);
}